// Round 10
// baseline (3058.103 us; speedup 1.0000x reference)
//
#include <hip/hip_runtime.h>
#include <stddef.h>

// ---------- types / helpers ----------
using short8 = __attribute__((ext_vector_type(8))) short;
using f32x4  = __attribute__((ext_vector_type(4))) float;
using f32x16 = __attribute__((ext_vector_type(16))) float;
using u16x4  = __attribute__((ext_vector_type(4))) unsigned short;
using u64    = unsigned long long;

__device__ __forceinline__ unsigned short cvt_bf16(float f) {
    unsigned u = __builtin_bit_cast(unsigned, f);
    u += 0x7fffu + ((u >> 16) & 1u);          // RNE
    return (unsigned short)(u >> 16);
}

__device__ __forceinline__ void gload_lds16(const void* g, void* l) {
    __builtin_amdgcn_global_load_lds(
        (const __attribute__((address_space(1))) unsigned*)g,
        (__attribute__((address_space(3))) unsigned*)l, 16, 0, 0);
}

#define AL64(p)      __hip_atomic_load((p), __ATOMIC_RELAXED, __HIP_MEMORY_SCOPE_AGENT)
#define AS64(p, v)   __hip_atomic_store((p), (v), __ATOMIC_RELAXED, __HIP_MEMORY_SCOPE_AGENT)

#define MFMA16(a, b, c) __builtin_amdgcn_mfma_f32_16x16x32_bf16((a), (b), (c), 0, 0, 0)
#define MFMA32(a, b, c) __builtin_amdgcn_mfma_f32_32x32x16_bf16((a), (b), (c), 0, 0, 0)

// B=128, T=256, I=H=K=1024
// ---------- weight conversion: f32 -> bf16 ----------
__global__ __launch_bounds__(256) void convert_w(const float* __restrict__ Wi,
                                                 const float* __restrict__ Wh,
                                                 unsigned short* __restrict__ Wib,
                                                 unsigned short* __restrict__ Whb) {
    const float* src = blockIdx.y ? Wh : Wi;
    unsigned short* dst = blockIdx.y ? Whb : Wib;
    int base = blockIdx.x * 2048 + threadIdx.x * 8;
#pragma unroll
    for (int c = 0; c < 2; ++c) {
        float4 v = *(const float4*)(src + base + c * 4);
        u16x4 o;
        o.x = cvt_bf16(v.x); o.y = cvt_bf16(v.y); o.z = cvt_bf16(v.z); o.w = cvt_bf16(v.w);
        *(u16x4*)(dst + base + c * 4) = o;
    }
}

// ---------- h init: tagged u32 (tag=1) into buf0, clear buf1 ----------
__global__ __launch_bounds__(256) void init_h(const float* __restrict__ hidden,
                                              unsigned* __restrict__ h32) {
    int row = blockIdx.x;
    int tid = threadIdx.x;
    float4 v = *(const float4*)(hidden + (size_t)row * 1024 + tid * 4);
    uint4 w;
    w.x = 0x10000u | cvt_bf16(v.x);
    w.y = 0x10000u | cvt_bf16(v.y);
    w.z = 0x10000u | cvt_bf16(v.z);
    w.w = 0x10000u | cvt_bf16(v.w);
    *(uint4*)(h32 + (size_t)row * 1024 + tid * 4) = w;
    uint4 z; z.x = z.y = z.z = z.w = 0u;
    *(uint4*)(h32 + 262144 + (size_t)row * 1024 + tid * 4) = z;
}

// ---------- pre-GEMM: pre[t][b][n] = sum_k x[b][t][k] * Wi[n][k] + bi[n] ----------
__global__ __launch_bounds__(256) void pre_gemm(const float* __restrict__ x,
                                                const unsigned short* __restrict__ Wib,
                                                const float* __restrict__ bi,
                                                float* __restrict__ pre) {
    __shared__ unsigned short Alds[128 * 64];
    __shared__ unsigned short Blds[128 * 64];
    const int tid  = threadIdx.x;
    const int lane = tid & 63, wid = tid >> 6;
    const int wr = wid >> 1, wc = wid & 1;     // 2x2 waves, 64x64 each
    const int t  = blockIdx.y;                 // time index == M-tile
    const int n0 = blockIdx.x * 128;

    f32x4 acc[4][4] = {};

    for (int kt = 0; kt < 16; ++kt) {
        const int k0 = kt * 64;
        __syncthreads();
#pragma unroll
        for (int c = 0; c < 8; ++c) {
            int flat = c * 256 + tid;          // 0..2047
            int row = flat >> 4;               // 0..127  (batch b)
            int seg = flat & 15;               // 16 segs of 4 f32
            float4 v = *(const float4*)(x + (size_t)row * 262144 + (size_t)t * 1024 + k0 + seg * 4);
            u16x4 h;
            h.x = cvt_bf16(v.x); h.y = cvt_bf16(v.y); h.z = cvt_bf16(v.z); h.w = cvt_bf16(v.w);
            *(u16x4*)&Alds[row * 64 + seg * 4] = h;
        }
#pragma unroll
        for (int c = 0; c < 4; ++c) {
            int flat = c * 256 + tid;          // 0..1023
            int row = flat >> 3;               // 0..127
            int seg = flat & 7;                // 8 segs of 8 bf16
            gload_lds16(Wib + (size_t)(n0 + row) * 1024 + k0 + seg * 8, &Blds[flat * 8]);
        }
        __syncthreads();
#pragma unroll
        for (int ks = 0; ks < 2; ++ks) {
            short8 a[4], b[4];
#pragma unroll
            for (int i = 0; i < 4; ++i)
                a[i] = *(const short8*)&Alds[(wr * 64 + i * 16 + (lane & 15)) * 64 + ks * 32 + (lane >> 4) * 8];
#pragma unroll
            for (int j = 0; j < 4; ++j)
                b[j] = *(const short8*)&Blds[(wc * 64 + j * 16 + (lane & 15)) * 64 + ks * 32 + (lane >> 4) * 8];
#pragma unroll
            for (int i = 0; i < 4; ++i)
#pragma unroll
                for (int j = 0; j < 4; ++j)
                    acc[i][j] = MFMA16(a[i], b[j], acc[i][j]);
        }
    }
    const int rbase = wr * 64 + (lane >> 4) * 4;
    const int cbase = n0 + wc * 64 + (lane & 15);
#pragma unroll
    for (int i = 0; i < 4; ++i) {
#pragma unroll
        for (int j = 0; j < 4; ++j) {
            int n = cbase + j * 16;
            float bv = bi[n];
#pragma unroll
            for (int r = 0; r < 4; ++r) {
                int m = rbase + i * 16 + r;    // batch b
                pre[((size_t)t * 128 + m) * 1024 + n] = acc[i][j][r] + bv;
            }
        }
    }
}

// ---------- persistent scan kernel, tag-in-data sync ----------
// 256 blocks x 256 threads. group g = bid&7 (g<4: fwd rows g*32.., g>=4: bwd),
// ni = bid>>3 -> cols ni*32. h stored as u32 = (tag<<16)|bf16 in 2 ping-pong
// buffers; iteration s consumes tag s+1 from buf[s&1], produces tag s+2 into
// buf[(s+1)&1]. Producer: fire-and-forget stores (no ack, no flags, no 3rd
// barrier). Consumer: poll IS the load (re-issue untagged rows). Tag ABA-free:
// stale tag in a buffer is s-1 != s+1.
__global__ __launch_bounds__(256, 1) void rnn_scan(const unsigned short* __restrict__ Whb,
                                                   const float* __restrict__ pre,
                                                   const float* __restrict__ bh,
                                                   unsigned* __restrict__ h32,
                                                   float* __restrict__ out) {
    __shared__ unsigned short Alds[32 * 1024];   // 64KB h-slice, XOR-swizzled
    __shared__ float Red[4][1024];               // 16KB cross-wave reduce

    const int tid  = threadIdx.x;
    const int lane = tid & 63, wid = tid >> 6;
    const int bid  = blockIdx.x;
    const int g    = bid & 7, ni = bid >> 3;
    const int m0   = g * 32, n0 = ni * 32;
    const bool fwd = (g < 4);

    // Wh b-frags resident: wave wid owns k in [wid*256, wid*256+256)
    short8 bfrag[16];
    {
        const unsigned short* bp = Whb + (size_t)(n0 + (lane & 31)) * 1024
                                 + wid * 256 + (lane >> 5) * 8;
#pragma unroll
        for (int ks = 0; ks < 16; ++ks)
            bfrag[ks] = *(const short8*)(bp + ks * 16);
    }

    // epilogue constants: thread owns 4 consecutive n at one row
    const int mloc = tid >> 3;            // 0..31
    const int nloc = (tid & 7) * 4;       // 0..28
    const int mg   = m0 + mloc;
    const int b    = mg & 127;
    const int n    = n0 + nloc;
    const f32x4 bh4 = *(const f32x4*)(bh + n);
    const float* prebase = pre + (size_t)b * 1024 + n;
    float* outp          = out + (size_t)b * 524288 + (fwd ? 0 : 1024) + n;

    const int   colswz = tid * 8;
    const char* arow   = (const char*)Alds + (lane & 31) * 2048;
    const int   aswz   = (lane & 15) << 4;
    const int   kb0    = wid * 512 + (lane >> 5) * 16;

    for (int s = 0; s < 256; ++s) {
        const unsigned want = (unsigned)(s + 1);
        const u64 wantpat = ((u64)want << 16) | ((u64)want << 48);
        const u64* src = (const u64*)(h32 + (size_t)(s & 1) * 262144 + (size_t)m0 * 1024) + tid * 2;
        u64*       dst = (u64*)(h32 + (size_t)((s + 1) & 1) * 262144 + (size_t)mg * 1024 + n);
        const int prow = fwd ? s : 255 - s;

        // pre tile prefetch (independent of h)
        const f32x4 pv = *(const f32x4*)(prebase + (size_t)prow * 131072);

        // poll+gather: 32 rows x 16B (as 2 u64 each); re-issue untagged rows
        u64 va[32], vb[32];
#pragma unroll
        for (int i = 0; i < 32; ++i) {
            va[i] = AL64(src + (size_t)i * 512);
            vb[i] = AL64(src + (size_t)i * 512 + 1);
        }
        {
            unsigned pend = 0xffffffffu;
            int fuel = 1 << 22;
            while (pend && fuel) {
                unsigned np = 0;
#pragma unroll
                for (int i = 0; i < 32; ++i) {
                    if ((pend >> i) & 1u) {
                        if ((((va[i] ^ wantpat) | (vb[i] ^ wantpat))
                             & 0xFFFF0000FFFF0000ull) != 0ull) {
                            va[i] = AL64(src + (size_t)i * 512);
                            vb[i] = AL64(src + (size_t)i * 512 + 1);
                            np |= 1u << i;
                        }
                    }
                }
                pend = np;
                --fuel;
            }
        }
        // extract bf16 payloads -> swizzled ds_write
#pragma unroll
        for (int i = 0; i < 32; ++i) {
            unsigned lo = (unsigned)(va[i] & 0xffffu) | ((unsigned)(va[i] >> 16) & 0xffff0000u);
            unsigned hi = (unsigned)(vb[i] & 0xffffu) | ((unsigned)(vb[i] >> 16) & 0xffff0000u);
            *(u64*)((char*)Alds + i * 2048 + (colswz ^ ((i & 15) << 4))) =
                (u64)lo | ((u64)hi << 32);
        }
        __syncthreads();                                   // S1

        // K-split MFMA: each wave 32x32 partial over its K=256 slice
        f32x16 acc0 = {}, acc1 = {};
#pragma unroll
        for (int ks = 0; ks < 16; ++ks) {
            short8 a = *(const short8*)(arow + ((kb0 + ks * 32) ^ aswz));
            if (ks & 1) acc1 = MFMA32(a, bfrag[ks], acc1);
            else        acc0 = MFMA32(a, bfrag[ks], acc0);
        }
        f32x16 acc = acc0 + acc1;
#pragma unroll
        for (int r = 0; r < 16; ++r) {
            int row = (r & 3) + 8 * (r >> 2) + 4 * (lane >> 5);
            Red[wid][row * 32 + (lane & 31)] = acc[r];
        }
        __syncthreads();                                   // S2

        // reduce + softplus + fire-and-forget tagged h-store + out
        {
            const int o = tid * 4;
            f32x4 q0 = *(const f32x4*)&Red[0][o];
            f32x4 q1 = *(const f32x4*)&Red[1][o];
            f32x4 q2 = *(const f32x4*)&Red[2][o];
            f32x4 q3 = *(const f32x4*)&Red[3][o];
            f32x4 vv = q0 + q1 + q2 + q3 + pv + bh4;
            f32x4 ov;
            u16x4 hh;
#pragma unroll
            for (int j = 0; j < 4; ++j) {
                float xv = vv[j];
                float hv = (5.0f * xv > 20.0f) ? xv : 0.2f * log1pf(__expf(5.0f * xv));
                ov[j] = hv;
                hh[j] = cvt_bf16(hv);
            }
            const unsigned ptag = (unsigned)(s + 2) << 16;
            u64 w0 = (u64)(ptag | (unsigned)(unsigned short)hh[0])
                   | ((u64)(ptag | (unsigned)(unsigned short)hh[1]) << 32);
            u64 w1 = (u64)(ptag | (unsigned)(unsigned short)hh[2])
                   | ((u64)(ptag | (unsigned)(unsigned short)hh[3]) << 32);
            AS64(dst, w0);
            AS64(dst + 1, w1);
            const int tout = fwd ? ((239 - s) & 255) : s;
            __builtin_nontemporal_store(ov, (f32x4*)(outp + (size_t)tout * 2048));
        }
    }
}

// ---------- launch ----------
extern "C" void kernel_launch(void* const* d_in, const int* in_sizes, int n_in,
                              void* d_out, int out_size, void* d_ws, size_t ws_size,
                              hipStream_t stream) {
    const float* x      = (const float*)d_in[0];
    const float* hidden = (const float*)d_in[1];
    const float* Wi     = (const float*)d_in[2];
    const float* bi     = (const float*)d_in[3];
    const float* Wh     = (const float*)d_in[4];
    const float* bh     = (const float*)d_in[5];
    float* out = (float*)d_out;

    char* ws = (char*)d_ws;
    float*          pre = (float*)ws;                               // 128 MB
    unsigned short* Wib = (unsigned short*)(ws + 134217728);        // 2 MB
    unsigned short* Whb = (unsigned short*)(ws + 136314880);        // 2 MB
    unsigned*       h32 = (unsigned*)(ws + 138412032);              // 2 MB tagged h

    convert_w<<<dim3(512, 2), 256, 0, stream>>>(Wi, Wh, Wib, Whb);
    init_h<<<256, 256, 0, stream>>>(hidden, h32);
    pre_gemm<<<dim3(8, 256), 256, 0, stream>>>(x, Wib, bi, pre);
    rnn_scan<<<256, 256, 0, stream>>>(Whb, pre, bh, h32, out);
}

// Round 11
// 1544.961 us; speedup vs baseline: 1.9794x; 1.9794x over previous
//
#include <hip/hip_runtime.h>
#include <stddef.h>

// ---------- types / helpers ----------
using short8 = __attribute__((ext_vector_type(8))) short;
using f32x4  = __attribute__((ext_vector_type(4))) float;
using f32x16 = __attribute__((ext_vector_type(16))) float;
using u16x4  = __attribute__((ext_vector_type(4))) unsigned short;
using u64    = unsigned long long;

__device__ __forceinline__ unsigned short cvt_bf16(float f) {
    unsigned u = __builtin_bit_cast(unsigned, f);
    u += 0x7fffu + ((u >> 16) & 1u);          // RNE
    return (unsigned short)(u >> 16);
}

__device__ __forceinline__ void gload_lds16(const void* g, void* l) {
    __builtin_amdgcn_global_load_lds(
        (const __attribute__((address_space(1))) unsigned*)g,
        (__attribute__((address_space(3))) unsigned*)l, 16, 0, 0);
}

#define MFMA16(a, b, c) __builtin_amdgcn_mfma_f32_16x16x32_bf16((a), (b), (c), 0, 0, 0)
#define MFMA32(a, b, c) __builtin_amdgcn_mfma_f32_32x32x16_bf16((a), (b), (c), 0, 0, 0)

// B=128, T=256, I=H=K=1024
// ---------- weight conversion: f32 -> bf16 ----------
__global__ __launch_bounds__(256) void convert_w(const float* __restrict__ Wi,
                                                 const float* __restrict__ Wh,
                                                 unsigned short* __restrict__ Wib,
                                                 unsigned short* __restrict__ Whb) {
    const float* src = blockIdx.y ? Wh : Wi;
    unsigned short* dst = blockIdx.y ? Whb : Wib;
    int base = blockIdx.x * 2048 + threadIdx.x * 8;
#pragma unroll
    for (int c = 0; c < 2; ++c) {
        float4 v = *(const float4*)(src + base + c * 4);
        u16x4 o;
        o.x = cvt_bf16(v.x); o.y = cvt_bf16(v.y); o.z = cvt_bf16(v.z); o.w = cvt_bf16(v.w);
        *(u16x4*)(dst + base + c * 4) = o;
    }
}

// ---------- h init + flag zero ----------
__global__ __launch_bounds__(256) void init_h(const float* __restrict__ hidden,
                                              unsigned short* __restrict__ h0,
                                              unsigned* __restrict__ flags) {
    int row = blockIdx.x;
    int tid = threadIdx.x;
    float4 v = *(const float4*)(hidden + (size_t)row * 1024 + tid * 4);
    u16x4 o;
    o.x = cvt_bf16(v.x); o.y = cvt_bf16(v.y); o.z = cvt_bf16(v.z); o.w = cvt_bf16(v.w);
    *(u16x4*)(h0 + (size_t)row * 1024 + tid * 4) = o;
    if (blockIdx.x == 0) {
        for (int i = tid; i < 512; i += 256) flags[i] = 0;
    }
}

// ---------- pre-GEMM: pre[t][b][n] = sum_k x[b][t][k] * Wi[n][k] + bi[n] ----------
__global__ __launch_bounds__(256) void pre_gemm(const float* __restrict__ x,
                                                const unsigned short* __restrict__ Wib,
                                                const float* __restrict__ bi,
                                                float* __restrict__ pre) {
    __shared__ unsigned short Alds[128 * 64];
    __shared__ unsigned short Blds[128 * 64];
    const int tid  = threadIdx.x;
    const int lane = tid & 63, wid = tid >> 6;
    const int wr = wid >> 1, wc = wid & 1;     // 2x2 waves, 64x64 each
    const int t  = blockIdx.y;                 // time index == M-tile
    const int n0 = blockIdx.x * 128;

    f32x4 acc[4][4] = {};

    for (int kt = 0; kt < 16; ++kt) {
        const int k0 = kt * 64;
        __syncthreads();
#pragma unroll
        for (int c = 0; c < 8; ++c) {
            int flat = c * 256 + tid;          // 0..2047
            int row = flat >> 4;               // 0..127  (batch b)
            int seg = flat & 15;               // 16 segs of 4 f32
            float4 v = *(const float4*)(x + (size_t)row * 262144 + (size_t)t * 1024 + k0 + seg * 4);
            u16x4 h;
            h.x = cvt_bf16(v.x); h.y = cvt_bf16(v.y); h.z = cvt_bf16(v.z); h.w = cvt_bf16(v.w);
            *(u16x4*)&Alds[row * 64 + seg * 4] = h;
        }
#pragma unroll
        for (int c = 0; c < 4; ++c) {
            int flat = c * 256 + tid;          // 0..1023
            int row = flat >> 3;               // 0..127
            int seg = flat & 7;                // 8 segs of 8 bf16
            gload_lds16(Wib + (size_t)(n0 + row) * 1024 + k0 + seg * 8, &Blds[flat * 8]);
        }
        __syncthreads();
#pragma unroll
        for (int ks = 0; ks < 2; ++ks) {
            short8 a[4], b[4];
#pragma unroll
            for (int i = 0; i < 4; ++i)
                a[i] = *(const short8*)&Alds[(wr * 64 + i * 16 + (lane & 15)) * 64 + ks * 32 + (lane >> 4) * 8];
#pragma unroll
            for (int j = 0; j < 4; ++j)
                b[j] = *(const short8*)&Blds[(wc * 64 + j * 16 + (lane & 15)) * 64 + ks * 32 + (lane >> 4) * 8];
#pragma unroll
            for (int i = 0; i < 4; ++i)
#pragma unroll
                for (int j = 0; j < 4; ++j)
                    acc[i][j] = MFMA16(a[i], b[j], acc[i][j]);
        }
    }
    const int rbase = wr * 64 + (lane >> 4) * 4;
    const int cbase = n0 + wc * 64 + (lane & 15);
#pragma unroll
    for (int i = 0; i < 4; ++i) {
#pragma unroll
        for (int j = 0; j < 4; ++j) {
            int n = cbase + j * 16;
            float bv = bi[n];
#pragma unroll
            for (int r = 0; r < 4; ++r) {
                int m = rbase + i * 16 + r;    // batch b
                pre[((size_t)t * 128 + m) * 1024 + n] = acc[i][j][r] + bv;
            }
        }
    }
}

// ---------- persistent scan kernel ----------
// 256 blocks x 256 threads. group g = bid&7 (g<4: fwd rows g*32.., g>=4: bwd),
// ni = bid>>3 -> cols ni*32. h traffic relaxed agent-scope (IFC-coherent).
// Per-THREAD poll: thread tid's gather bytes [tid*8,tid*8+8) of every h row
// come from exactly one producer (ni = tid>>3), so each thread polls ONE flag
// and gathers as soon as ITS producer published — straggler wait overlaps
// with the other producers' gathers; max-of-32 is absorbed at the S1 barrier.
__global__ __launch_bounds__(256, 1) void rnn_scan(const unsigned short* __restrict__ Whb,
                                                   const float* __restrict__ pre,
                                                   const float* __restrict__ bh,
                                                   unsigned short* __restrict__ ha,
                                                   unsigned short* __restrict__ hb,
                                                   float* __restrict__ out,
                                                   unsigned* __restrict__ flags) {
    __shared__ unsigned short Alds[32 * 1024];   // 64KB h-slice, XOR-swizzled
    __shared__ float Red[4][1024];               // 16KB cross-wave reduce

    const int tid  = threadIdx.x;
    const int lane = tid & 63, wid = tid >> 6;
    const int bid  = blockIdx.x;
    const int g    = bid & 7, ni = bid >> 3;
    const int m0   = g * 32, n0 = ni * 32;
    const bool fwd = (g < 4);
    unsigned* gflags = flags + g * 32;

    // Wh b-frags resident: wave wid owns k in [wid*256, wid*256+256)
    short8 bfrag[16];
    {
        const unsigned short* bp = Whb + (size_t)(n0 + (lane & 31)) * 1024
                                 + wid * 256 + (lane >> 5) * 8;
#pragma unroll
        for (int ks = 0; ks < 16; ++ks)
            bfrag[ks] = *(const short8*)(bp + ks * 16);
    }

    // epilogue constants: thread owns 4 consecutive n at one row
    const int mloc = tid >> 3;            // 0..31
    const int nloc = (tid & 7) * 4;       // 0..28
    const int mg   = m0 + mloc;
    const int b    = mg & 127;
    const int n    = n0 + nloc;
    const f32x4 bh4 = *(const f32x4*)(bh + n);
    const float* prebase = pre + (size_t)b * 1024 + n;
    float* outp          = out + (size_t)b * 524288 + (fwd ? 0 : 1024) + n;

    const int   colswz = tid * 8;
    const char* arow   = (const char*)Alds + (lane & 31) * 2048;
    const int   aswz   = (lane & 15) << 4;       // row&15 swizzle (0 conflicts)
    const int   kb0    = wid * 512 + (lane >> 5) * 16;
    unsigned* myflag   = &gflags[tid >> 3];      // this thread's sole producer

    for (int s = 0; s < 256; ++s) {
        const unsigned short* hin = (s & 1) ? hb : ha;
        unsigned short* hout      = (s & 1) ? ha : hb;
        const int prow = fwd ? s : 255 - s;

        // pre tile prefetch (independent of h)
        const f32x4 pv = *(const f32x4*)(prebase + (size_t)prow * 131072);

        // per-thread poll of ONE producer flag
        if (s > 0) {
            int fuel = 1 << 22;
            unsigned v;
            do {
                v = __hip_atomic_load(myflag, __ATOMIC_RELAXED,
                                      __HIP_MEMORY_SCOPE_AGENT);
            } while (v < (unsigned)s && --fuel);
        }

        // gather this thread's 8B column slice of all 32 h rows -> swizzled LDS
        {
            const u64* hsrc = (const u64*)(hin + (size_t)m0 * 1024);
            u64 tmp[32];
#pragma unroll
            for (int i = 0; i < 32; ++i)
                tmp[i] = __hip_atomic_load(&hsrc[(size_t)i * 256 + tid],
                                           __ATOMIC_RELAXED, __HIP_MEMORY_SCOPE_AGENT);
#pragma unroll
            for (int i = 0; i < 32; ++i)
                *(u64*)((char*)Alds + i * 2048 + (colswz ^ ((i & 15) << 4))) = tmp[i];
        }
        __syncthreads();                                   // S1

        // K-split MFMA: each wave 32x32 partial over its K=256 slice
        f32x16 acc0 = {}, acc1 = {};
#pragma unroll
        for (int ks = 0; ks < 16; ++ks) {
            short8 a = *(const short8*)(arow + ((kb0 + ks * 32) ^ aswz));
            if (ks & 1) acc1 = MFMA32(a, bfrag[ks], acc1);
            else        acc0 = MFMA32(a, bfrag[ks], acc0);
        }
        f32x16 acc = acc0 + acc1;
#pragma unroll
        for (int r = 0; r < 16; ++r) {
            int row = (r & 3) + 8 * (r >> 2) + 4 * (lane >> 5);
            Red[wid][row * 32 + (lane & 31)] = acc[r];
        }
        __syncthreads();                                   // S2

        // reduce 4 waves + epilogue
        f32x4 ov;
        {
            const int o = tid * 4;
            f32x4 q0 = *(const f32x4*)&Red[0][o];
            f32x4 q1 = *(const f32x4*)&Red[1][o];
            f32x4 q2 = *(const f32x4*)&Red[2][o];
            f32x4 q3 = *(const f32x4*)&Red[3][o];
            f32x4 vv = q0 + q1 + q2 + q3 + pv + bh4;
            u16x4 hh;
#pragma unroll
            for (int j = 0; j < 4; ++j) {
                float xv = vv[j];
                float hv = (5.0f * xv > 20.0f) ? xv : 0.2f * log1pf(__expf(5.0f * xv));
                ov[j] = hv;
                hh[j] = cvt_bf16(hv);
            }
            __hip_atomic_store((u64*)(hout + (size_t)mg * 1024 + n),
                               __builtin_bit_cast(u64, hh),
                               __ATOMIC_RELAXED, __HIP_MEMORY_SCOPE_AGENT);
        }
        asm volatile("s_waitcnt vmcnt(0)" ::: "memory");   // h stores acked
        __syncthreads();                                   // S3

        if (s < 255 && tid == 0)
            __hip_atomic_store(&gflags[ni], (unsigned)(s + 1),
                               __ATOMIC_RELAXED, __HIP_MEMORY_SCOPE_AGENT);

        // out store AFTER flag publish (off the critical path)
        const int tout = fwd ? ((239 - s) & 255) : s;
        __builtin_nontemporal_store(ov, (f32x4*)(outp + (size_t)tout * 2048));
    }
}

// ---------- launch ----------
extern "C" void kernel_launch(void* const* d_in, const int* in_sizes, int n_in,
                              void* d_out, int out_size, void* d_ws, size_t ws_size,
                              hipStream_t stream) {
    const float* x      = (const float*)d_in[0];
    const float* hidden = (const float*)d_in[1];
    const float* Wi     = (const float*)d_in[2];
    const float* bi     = (const float*)d_in[3];
    const float* Wh     = (const float*)d_in[4];
    const float* bh     = (const float*)d_in[5];
    float* out = (float*)d_out;

    char* ws = (char*)d_ws;
    float*          pre = (float*)ws;                               // 128 MB
    unsigned short* Wib = (unsigned short*)(ws + 134217728);        // 2 MB
    unsigned short* Whb = (unsigned short*)(ws + 136314880);        // 2 MB
    unsigned short* ha  = (unsigned short*)(ws + 138412032);        // 512 KB
    unsigned short* hb  = (unsigned short*)(ws + 138936320);        // 512 KB
    unsigned*     flags = (unsigned*)(ws + 139460608);              // 2 KB

    convert_w<<<dim3(512, 2), 256, 0, stream>>>(Wi, Wh, Wib, Whb);
    init_h<<<256, 256, 0, stream>>>(hidden, ha, flags);
    pre_gemm<<<dim3(8, 256), 256, 0, stream>>>(x, Wib, bi, pre);
    rnn_scan<<<256, 256, 0, stream>>>(Whb, pre, bh, ha, hb, out, flags);
}

// Round 12
// 1355.012 us; speedup vs baseline: 2.2569x; 1.1402x over previous
//
#include <hip/hip_runtime.h>
#include <stddef.h>

// ---------- types / helpers ----------
using short8 = __attribute__((ext_vector_type(8))) short;
using f32x4  = __attribute__((ext_vector_type(4))) float;
using f32x16 = __attribute__((ext_vector_type(16))) float;
using u16x4  = __attribute__((ext_vector_type(4))) unsigned short;
using u64    = unsigned long long;

__device__ __forceinline__ unsigned short cvt_bf16(float f) {
    unsigned u = __builtin_bit_cast(unsigned, f);
    u += 0x7fffu + ((u >> 16) & 1u);          // RNE
    return (unsigned short)(u >> 16);
}

__device__ __forceinline__ void gload_lds16(const void* g, void* l) {
    __builtin_amdgcn_global_load_lds(
        (const __attribute__((address_space(1))) unsigned*)g,
        (__attribute__((address_space(3))) unsigned*)l, 16, 0, 0);
}

#define AL32(p)    __hip_atomic_load((p), __ATOMIC_RELAXED, __HIP_MEMORY_SCOPE_AGENT)
#define AS32(p, v) __hip_atomic_store((p), (v), __ATOMIC_RELAXED, __HIP_MEMORY_SCOPE_AGENT)

#define MFMA16(a, b, c) __builtin_amdgcn_mfma_f32_16x16x32_bf16((a), (b), (c), 0, 0, 0)
#define MFMA32(a, b, c) __builtin_amdgcn_mfma_f32_32x32x16_bf16((a), (b), (c), 0, 0, 0)

// B=128, T=256, I=H=K=1024
// flag layout: slot (g*32+ni) = 64 u32 (256B); sub-flag w at slot[w], rest pad.

// ---------- weight conversion: f32 -> bf16 ----------
__global__ __launch_bounds__(256) void convert_w(const float* __restrict__ Wi,
                                                 const float* __restrict__ Wh,
                                                 unsigned short* __restrict__ Wib,
                                                 unsigned short* __restrict__ Whb) {
    const float* src = blockIdx.y ? Wh : Wi;
    unsigned short* dst = blockIdx.y ? Whb : Wib;
    int base = blockIdx.x * 2048 + threadIdx.x * 8;
#pragma unroll
    for (int c = 0; c < 2; ++c) {
        float4 v = *(const float4*)(src + base + c * 4);
        u16x4 o;
        o.x = cvt_bf16(v.x); o.y = cvt_bf16(v.y); o.z = cvt_bf16(v.z); o.w = cvt_bf16(v.w);
        *(u16x4*)(dst + base + c * 4) = o;
    }
}

// ---------- h init + padded flag zero ----------
__global__ __launch_bounds__(256) void init_h(const float* __restrict__ hidden,
                                              unsigned short* __restrict__ h0,
                                              unsigned* __restrict__ flags) {
    int row = blockIdx.x;
    int tid = threadIdx.x;
    float4 v = *(const float4*)(hidden + (size_t)row * 1024 + tid * 4);
    u16x4 o;
    o.x = cvt_bf16(v.x); o.y = cvt_bf16(v.y); o.z = cvt_bf16(v.z); o.w = cvt_bf16(v.w);
    *(u16x4*)(h0 + (size_t)row * 1024 + tid * 4) = o;
    if (tid < 64) flags[(size_t)row * 64 + tid] = 0;   // 256 slots x 64 u32
}

// ---------- pre-GEMM: pre[t][b][n] = sum_k x[b][t][k] * Wi[n][k] + bi[n] ----------
__global__ __launch_bounds__(256) void pre_gemm(const float* __restrict__ x,
                                                const unsigned short* __restrict__ Wib,
                                                const float* __restrict__ bi,
                                                float* __restrict__ pre) {
    __shared__ unsigned short Alds[128 * 64];
    __shared__ unsigned short Blds[128 * 64];
    const int tid  = threadIdx.x;
    const int lane = tid & 63, wid = tid >> 6;
    const int wr = wid >> 1, wc = wid & 1;     // 2x2 waves, 64x64 each
    const int t  = blockIdx.y;                 // time index == M-tile
    const int n0 = blockIdx.x * 128;

    f32x4 acc[4][4] = {};

    for (int kt = 0; kt < 16; ++kt) {
        const int k0 = kt * 64;
        __syncthreads();
#pragma unroll
        for (int c = 0; c < 8; ++c) {
            int flat = c * 256 + tid;          // 0..2047
            int row = flat >> 4;               // 0..127  (batch b)
            int seg = flat & 15;               // 16 segs of 4 f32
            float4 v = *(const float4*)(x + (size_t)row * 262144 + (size_t)t * 1024 + k0 + seg * 4);
            u16x4 h;
            h.x = cvt_bf16(v.x); h.y = cvt_bf16(v.y); h.z = cvt_bf16(v.z); h.w = cvt_bf16(v.w);
            *(u16x4*)&Alds[row * 64 + seg * 4] = h;
        }
#pragma unroll
        for (int c = 0; c < 4; ++c) {
            int flat = c * 256 + tid;          // 0..1023
            int row = flat >> 3;               // 0..127
            int seg = flat & 7;                // 8 segs of 8 bf16
            gload_lds16(Wib + (size_t)(n0 + row) * 1024 + k0 + seg * 8, &Blds[flat * 8]);
        }
        __syncthreads();
#pragma unroll
        for (int ks = 0; ks < 2; ++ks) {
            short8 a[4], b[4];
#pragma unroll
            for (int i = 0; i < 4; ++i)
                a[i] = *(const short8*)&Alds[(wr * 64 + i * 16 + (lane & 15)) * 64 + ks * 32 + (lane >> 4) * 8];
#pragma unroll
            for (int j = 0; j < 4; ++j)
                b[j] = *(const short8*)&Blds[(wc * 64 + j * 16 + (lane & 15)) * 64 + ks * 32 + (lane >> 4) * 8];
#pragma unroll
            for (int i = 0; i < 4; ++i)
#pragma unroll
                for (int j = 0; j < 4; ++j)
                    acc[i][j] = MFMA16(a[i], b[j], acc[i][j]);
        }
    }
    const int rbase = wr * 64 + (lane >> 4) * 4;
    const int cbase = n0 + wc * 64 + (lane & 15);
#pragma unroll
    for (int i = 0; i < 4; ++i) {
#pragma unroll
        for (int j = 0; j < 4; ++j) {
            int n = cbase + j * 16;
            float bv = bi[n];
#pragma unroll
            for (int r = 0; r < 4; ++r) {
                int m = rbase + i * 16 + r;    // batch b
                pre[((size_t)t * 128 + m) * 1024 + n] = acc[i][j][r] + bv;
            }
        }
    }
}

// ---------- persistent scan kernel ----------
// 256 blocks x 256 threads. group g = bid&7 (g<4: fwd rows g*32.., g>=4: bwd),
// ni = bid>>3 -> cols ni*32. h traffic relaxed agent-scope (IFC-coherent).
// Sync: per-producer 256B-padded slot with 4 per-wave sub-flags. Every wave
// polls uniformly (no post-poll barrier); each wave acks its own h-stores and
// publishes its sub-flag (no 3rd barrier). 2 syncthreads/step.
__global__ __launch_bounds__(256, 1) void rnn_scan(const unsigned short* __restrict__ Whb,
                                                   const float* __restrict__ pre,
                                                   const float* __restrict__ bh,
                                                   unsigned short* __restrict__ ha,
                                                   unsigned short* __restrict__ hb,
                                                   float* __restrict__ out,
                                                   unsigned* __restrict__ flags) {
    __shared__ unsigned short Alds[32 * 1024];   // 64KB h-slice, XOR-swizzled
    __shared__ float Red[4][1024];               // 16KB cross-wave reduce

    const int tid  = threadIdx.x;
    const int lane = tid & 63, wid = tid >> 6;
    const int bid  = blockIdx.x;
    const int g    = bid & 7, ni = bid >> 3;
    const int m0   = g * 32, n0 = ni * 32;
    const bool fwd = (g < 4);

    // Wh b-frags resident: wave wid owns k in [wid*256, wid*256+256)
    short8 bfrag[16];
    {
        const unsigned short* bp = Whb + (size_t)(n0 + (lane & 31)) * 1024
                                 + wid * 256 + (lane >> 5) * 8;
#pragma unroll
        for (int ks = 0; ks < 16; ++ks)
            bfrag[ks] = *(const short8*)(bp + ks * 16);
    }

    // epilogue constants: thread owns 4 consecutive n at one row
    const int mloc = tid >> 3;            // 0..31
    const int nloc = (tid & 7) * 4;       // 0..28
    const int mg   = m0 + mloc;
    const int b    = mg & 127;
    const int n    = n0 + nloc;
    const f32x4 bh4 = *(const f32x4*)(bh + n);
    const float* prebase = pre + (size_t)b * 1024 + n;
    float* outp          = out + (size_t)b * 524288 + (fwd ? 0 : 1024) + n;

    const int   colswz = tid * 8;
    const char* arow   = (const char*)Alds + (lane & 31) * 2048;
    const int   aswz   = (lane & 15) << 4;       // 0-conflict swizzle
    const int   kb0    = wid * 512 + (lane >> 5) * 16;

    // poll addresses: lane watches producer (lane&31), sub-flags (lane>>5), 2+(lane>>5)
    const unsigned* pf0 = flags + (size_t)(g * 32 + (lane & 31)) * 64 + (lane >> 5);
    const unsigned* pf1 = pf0 + 2;
    // publish address: this block's slot, this wave's sub-flag
    unsigned* myflag = flags + (size_t)(g * 32 + ni) * 64 + wid;

    for (int s = 0; s < 256; ++s) {
        const unsigned short* hin = (s & 1) ? hb : ha;
        unsigned short* hout      = (s & 1) ? ha : hb;
        const int prow = fwd ? s : 255 - s;

        // pre tile prefetch (independent of h)
        const f32x4 pv = *(const f32x4*)(prebase + (size_t)prow * 131072);

        // uniform per-wave poll, padded slots, no post-poll barrier
        if (s > 0) {
            int fuel = 1 << 22;
            unsigned va, vb;
            do {
                va = AL32(pf0);
                vb = AL32(pf1);
            } while (!__all((int)(va >= (unsigned)s && vb >= (unsigned)s)) && --fuel);
        }

        // gather this thread's 8B column slice of all 32 h rows -> swizzled LDS
        {
            const u64* hsrc = (const u64*)(hin + (size_t)m0 * 1024);
            u64 tmp[32];
#pragma unroll
            for (int i = 0; i < 32; ++i)
                tmp[i] = __hip_atomic_load(&hsrc[(size_t)i * 256 + tid],
                                           __ATOMIC_RELAXED, __HIP_MEMORY_SCOPE_AGENT);
#pragma unroll
            for (int i = 0; i < 32; ++i)
                *(u64*)((char*)Alds + i * 2048 + (colswz ^ ((i & 15) << 4))) = tmp[i];
        }
        __syncthreads();                                   // S1

        // K-split MFMA: each wave 32x32 partial over its K=256 slice
        f32x16 acc0 = {}, acc1 = {};
#pragma unroll
        for (int ks = 0; ks < 16; ++ks) {
            short8 a = *(const short8*)(arow + ((kb0 + ks * 32) ^ aswz));
            if (ks & 1) acc1 = MFMA32(a, bfrag[ks], acc1);
            else        acc0 = MFMA32(a, bfrag[ks], acc0);
        }
        f32x16 acc = acc0 + acc1;
#pragma unroll
        for (int r = 0; r < 16; ++r) {
            int row = (r & 3) + 8 * (r >> 2) + 4 * (lane >> 5);
            Red[wid][row * 32 + (lane & 31)] = acc[r];
        }
        __syncthreads();                                   // S2

        // reduce 4 waves + epilogue; per-wave ack + sub-flag publish (no S3)
        f32x4 ov;
        {
            const int o = tid * 4;
            f32x4 q0 = *(const f32x4*)&Red[0][o];
            f32x4 q1 = *(const f32x4*)&Red[1][o];
            f32x4 q2 = *(const f32x4*)&Red[2][o];
            f32x4 q3 = *(const f32x4*)&Red[3][o];
            f32x4 vv = q0 + q1 + q2 + q3 + pv + bh4;
            u16x4 hh;
#pragma unroll
            for (int j = 0; j < 4; ++j) {
                float xv = vv[j];
                float hv = (5.0f * xv > 20.0f) ? xv : 0.2f * log1pf(__expf(5.0f * xv));
                ov[j] = hv;
                hh[j] = cvt_bf16(hv);
            }
            __hip_atomic_store((u64*)(hout + (size_t)mg * 1024 + n),
                               __builtin_bit_cast(u64, hh),
                               __ATOMIC_RELAXED, __HIP_MEMORY_SCOPE_AGENT);
        }
        asm volatile("s_waitcnt vmcnt(0)" ::: "memory");   // this wave's stores acked
        if (lane == 0 && s < 255)
            AS32(myflag, (unsigned)(s + 1));

        // out store AFTER publish (off the critical path)
        const int tout = fwd ? ((239 - s) & 255) : s;
        __builtin_nontemporal_store(ov, (f32x4*)(outp + (size_t)tout * 2048));
    }
}

// ---------- launch ----------
extern "C" void kernel_launch(void* const* d_in, const int* in_sizes, int n_in,
                              void* d_out, int out_size, void* d_ws, size_t ws_size,
                              hipStream_t stream) {
    const float* x      = (const float*)d_in[0];
    const float* hidden = (const float*)d_in[1];
    const float* Wi     = (const float*)d_in[2];
    const float* bi     = (const float*)d_in[3];
    const float* Wh     = (const float*)d_in[4];
    const float* bh     = (const float*)d_in[5];
    float* out = (float*)d_out;

    char* ws = (char*)d_ws;
    float*          pre = (float*)ws;                               // 128 MB
    unsigned short* Wib = (unsigned short*)(ws + 134217728);        // 2 MB
    unsigned short* Whb = (unsigned short*)(ws + 136314880);        // 2 MB
    unsigned short* ha  = (unsigned short*)(ws + 138412032);        // 512 KB
    unsigned short* hb  = (unsigned short*)(ws + 138936320);        // 512 KB
    unsigned*     flags = (unsigned*)(ws + 139460608);              // 64 KB padded

    convert_w<<<dim3(512, 2), 256, 0, stream>>>(Wi, Wh, Wib, Whb);
    init_h<<<256, 256, 0, stream>>>(hidden, ha, flags);
    pre_gemm<<<dim3(8, 256), 256, 0, stream>>>(x, Wib, bi, pre);
    rnn_scan<<<256, 256, 0, stream>>>(Whb, pre, bh, ha, hb, out, flags);
}